// Round 4
// baseline (288.952 us; speedup 1.0000x reference)
//
#include <hip/hip_runtime.h>
#include <hip/hip_bf16.h>

#define S 64
#define HF 128
#define WF 128
#define HW (HF * WF)
#define SSQ (S * S)
#define CCH 256
#define NBOX 128                      // B * N
#define CROPS_ELEMS (134217728)      // NBOX * CCH * S * S
#define TILE_POS 1024                 // float4 slots -> 16 KB; worst tile <= 29x29=841

// ---------------- Kernel A: per-box theta + M ----------------
__global__ void prep_kernel(const float* __restrict__ obb,
                            float* __restrict__ theta_ws,
                            float* __restrict__ m_out) {
    int i = blockIdx.x * blockDim.x + threadIdx.x;
    if (i >= NBOX) return;
    const float* o = obb + i * 5;
    float cx = o[0], cy = o[1], w = o[2], h = o[3], deg = o[4];
    float cxf = cx * 0.125f;
    float cyf = cy * 0.125f;
    float wf = fmaxf(w, 1.0f) * 1.25f * 0.125f;
    float hf = fmaxf(h, 1.0f) * 1.25f * 0.125f;
    float ang = deg * 0.017453292519943295f;  // deg2rad
    float c_ = cosf(ang);
    float s_ = sinf(ang);
    float sx = wf * (2.0f / (float)WF);
    float sy = hf * (2.0f / (float)HF);
    float tx = cxf * (2.0f / (float)WF) - 1.0f;
    float ty = cyf * (2.0f / (float)HF) - 1.0f;
    float* th = theta_ws + i * 6;
    th[0] = c_ * sx;  th[1] = -s_ * sy; th[2] = tx;
    th[3] = s_ * sx;  th[4] = c_ * sy;  th[5] = ty;

    float A  = c_ * (wf / (float)S);
    float Bv = -s_ * (hf / (float)S);
    float A2 = s_ * (wf / (float)S);
    float B2 = c_ * (hf / (float)S);
    float Cx = cxf - 0.5f * (float)S * (A + Bv);
    float Cy = cyf - 0.5f * (float)S * (A2 + B2);
    float* m = m_out + i * 6;
    m[0] = A;  m[1] = Bv; m[2] = Cx;
    m[3] = A2; m[4] = B2; m[5] = Cy;
}

// ---------------- Kernel B: 4-channel float4 LDS tile sampling ----------------
// grid: NBOX * 16 regions. Block = 256 threads = one 16x16 crop region,
// 1 pixel/thread. Channel loop: 64 groups of 4 channels staged as float4.
__global__ __launch_bounds__(256, 8) void sample_kernel(
        const float* __restrict__ feat,
        const float* __restrict__ theta,
        float* __restrict__ out) {
    __shared__ float4 tile[TILE_POS];

    const int b   = blockIdx.x;
    const int reg = b & 15;
    const int box = b >> 4;
    const int rx  = reg & 3;
    const int ry  = reg >> 2;
    const int tid = threadIdx.x;
    const int x   = (rx << 4) + (tid & 15);
    const int y   = (ry << 4) + (tid >> 4);

    const float* th = theta + box * 6;
    // feature-pixel affine: ix = ax*fx + bxc*fy + cx_, fx,fy in (-1,1)
    const float ax  = th[0] * 64.0f, bxc = th[1] * 64.0f, cx_ = th[2] * 64.0f + 63.5f;
    const float ay  = th[3] * 64.0f, byc = th[4] * 64.0f, cy_ = th[5] * 64.0f + 63.5f;

    // region bbox in feature space (+1 for bilinear upper corner)
    const float fcx = (float)((rx << 5) + 16) * 0.015625f - 1.0f;  // region center fx
    const float fcy = (float)((ry << 5) + 16) * 0.015625f - 1.0f;
    const float fh  = 15.0f / 64.0f;                               // half-range in fx/fy
    const float cxq = ax * fcx + bxc * fcy + cx_;
    const float cyq = ay * fcx + byc * fcy + cy_;
    const float hxq = (fabsf(ax) + fabsf(bxc)) * fh;
    const float hyq = (fabsf(ay) + fabsf(byc)) * fh;
    const int tx0 = min(max((int)floorf(cxq - hxq), 0), WF - 1);
    const int tx1 = min(max((int)floorf(cxq + hxq) + 1, 0), WF - 1);
    const int ty0 = min(max((int)floorf(cyq - hyq), 0), HF - 1);
    const int ty1 = min(max((int)floorf(cyq + hyq) + 1, 0), HF - 1);
    const int tw  = tx1 - tx0 + 1;
    const int thh = ty1 - ty0 + 1;
    const int twp = tw | 1;           // odd float4-slot row stride
    const int n   = tw * thh;

    // per-pixel channel-invariant sampling params
    int a00, a10, a01, a11;
    float W00, W10, W01, W11;
    {
        float fx = (float)(2 * x + 1) * 0.015625f - 1.0f;
        float fy = (float)(2 * y + 1) * 0.015625f - 1.0f;
        float ix = ax * fx + bxc * fy + cx_;
        float iy = ay * fx + byc * fy + cy_;
        float x0f = floorf(ix), y0f = floorf(iy);
        int x0 = (int)x0f, y0 = (int)y0f;
        float wx1 = ix - x0f, wy1 = iy - y0f;
        float wx0 = 1.0f - wx1, wy0 = 1.0f - wy1;
        bool vx0 = (x0 >= 0) & (x0 < WF);
        bool vx1 = (x0 >= -1) & (x0 < WF - 1);
        bool vy0 = (y0 >= 0) & (y0 < HF);
        bool vy1 = (y0 >= -1) & (y0 < HF - 1);
        W00 = (vx0 & vy0) ? wx0 * wy0 : 0.0f;
        W10 = (vx1 & vy0) ? wx1 * wy0 : 0.0f;
        W01 = (vx0 & vy1) ? wx0 * wy1 : 0.0f;
        W11 = (vx1 & vy1) ? wx1 * wy1 : 0.0f;
        int x0c = min(max(x0, 0), WF - 1) - tx0;
        int y0c = min(max(y0, 0), HF - 1) - ty0;
        int x1c = min(max(x0 + 1, 0), WF - 1) - tx0;
        int y1c = min(max(y0 + 1, 0), HF - 1) - ty0;
        int xs = x1c - x0c;           // 0 or 1
        int ys = y1c - y0c;           // 0 or 1
        a00 = y0c * twp + x0c;
        a10 = a00 + xs;
        a01 = a00 + ys * twp;
        a11 = a01 + xs;
    }

    // tile-loader walking state (no division in the channel loop)
    const int qy0 = tid / tw;
    const int qx0 = tid - qy0 * tw;
    const int kq  = 256 / tw;
    const int rq  = 256 - kq * tw;
    const int lidx0 = qy0 * twp + qx0;
    const int gidx0 = (ty0 + qy0) * WF + tx0 + qx0;
    const int stepL = kq * twp + rq;
    const int stepG = (kq << 7) + rq;

    const float* fmb = feat + (size_t)(box >> 6) * (size_t)(CCH * HW);
    float* ob = out + (size_t)box * (size_t)(CCH * SSQ) + y * S + x;

    for (int cg = 0; cg < CCH / 4; ++cg) {
        const float* fc = fmb + (size_t)cg * (4 * HW);
        // ---- stage tile: 4 channels interleaved as float4 ----
        {
            int qx_ = qx0, lidx = lidx0, gidx = gidx0;
            for (int q = tid; q < n; q += 256) {
                float4 t;
                t.x = fc[gidx];
                t.y = fc[gidx + HW];
                t.z = fc[gidx + 2 * HW];
                t.w = fc[gidx + 3 * HW];
                tile[lidx] = t;
                qx_ += rq; lidx += stepL; gidx += stepG;
                if (qx_ >= tw) { qx_ -= tw; lidx += twp - tw; gidx += WF - tw; }
            }
        }
        __syncthreads();
        // ---- sample 1 pixel x 4 channels from LDS ----
        float4 c00 = tile[a00];
        float4 c10 = tile[a10];
        float4 c01 = tile[a01];
        float4 c11 = tile[a11];
        float v0 = c00.x * W00 + c10.x * W10 + c01.x * W01 + c11.x * W11;
        float v1 = c00.y * W00 + c10.y * W10 + c01.y * W01 + c11.y * W11;
        float v2 = c00.z * W00 + c10.z * W10 + c01.z * W01 + c11.z * W11;
        float v3 = c00.w * W00 + c10.w * W10 + c01.w * W01 + c11.w * W11;
        ob[0]       = v0;
        ob[SSQ]     = v1;
        ob[2 * SSQ] = v2;
        ob[3 * SSQ] = v3;
        ob += 4 * SSQ;
        __syncthreads();
    }
}

extern "C" void kernel_launch(void* const* d_in, const int* in_sizes, int n_in,
                              void* d_out, int out_size, void* d_ws, size_t ws_size,
                              hipStream_t stream) {
    const float* feat = (const float*)d_in[0];
    const float* obb  = (const float*)d_in[1];
    float* out = (float*)d_out;
    float* theta_ws = (float*)d_ws;
    float* m_out = out + CROPS_ELEMS;

    prep_kernel<<<1, 128, 0, stream>>>(obb, theta_ws, m_out);
    sample_kernel<<<NBOX * 16, 256, 0, stream>>>(feat, theta_ws, out);
}

// Round 5
// 156.047 us; speedup vs baseline: 1.8517x; 1.8517x over previous
//
#include <hip/hip_runtime.h>
#include <hip/hip_bf16.h>

#define S 64
#define HF 128
#define WF 128
#define HW (HF * WF)
#define SSQ (S * S)
#define CCH 256
#define NBOX 128                      // B * N
#define CROPS_ELEMS (134217728)      // NBOX * CCH * S * S
#define CHG 16                        // channels per block (8 float2 groups)
#define NGRP (CCH / CHG)              // 16 channel-group blocks per quadrant
#define TILE_F2 3264                  // float2 slots (26.1 KB); worst quadrant tile 57x57=3249

// ---------------- Kernel A: per-box theta + M ----------------
__global__ void prep_kernel(const float* __restrict__ obb,
                            float* __restrict__ theta_ws,
                            float* __restrict__ m_out) {
    int i = blockIdx.x * blockDim.x + threadIdx.x;
    if (i >= NBOX) return;
    const float* o = obb + i * 5;
    float cx = o[0], cy = o[1], w = o[2], h = o[3], deg = o[4];
    float cxf = cx * 0.125f;
    float cyf = cy * 0.125f;
    float wf = fmaxf(w, 1.0f) * 1.25f * 0.125f;
    float hf = fmaxf(h, 1.0f) * 1.25f * 0.125f;
    float ang = deg * 0.017453292519943295f;  // deg2rad
    float c_ = cosf(ang);
    float s_ = sinf(ang);
    float sx = wf * (2.0f / (float)WF);
    float sy = hf * (2.0f / (float)HF);
    float tx = cxf * (2.0f / (float)WF) - 1.0f;
    float ty = cyf * (2.0f / (float)HF) - 1.0f;
    float* th = theta_ws + i * 6;
    th[0] = c_ * sx;  th[1] = -s_ * sy; th[2] = tx;
    th[3] = s_ * sx;  th[4] = c_ * sy;  th[5] = ty;

    float A  = c_ * (wf / (float)S);
    float Bv = -s_ * (hf / (float)S);
    float A2 = s_ * (wf / (float)S);
    float B2 = c_ * (hf / (float)S);
    float Cx = cxf - 0.5f * (float)S * (A + Bv);
    float Cy = cyf - 0.5f * (float)S * (A2 + B2);
    float* m = m_out + i * 6;
    m[0] = A;  m[1] = Bv; m[2] = Cx;
    m[3] = A2; m[4] = B2; m[5] = Cy;
}

// ---------------- Kernel B: float2 (2-channel) LDS tile sampling ------------
// grid: NBOX * 4 quadrants * NGRP. Block = 256 threads = 32 rows x 8 groups
// of 4 consecutive x (float4 stores). 8 iterations of 2 channels (float2 tile).
__global__ __launch_bounds__(256, 6) void sample_kernel(
        const float* __restrict__ feat,
        const float* __restrict__ theta,
        float* __restrict__ out) {
    __shared__ float2 tile[TILE_F2];

    const int b    = blockIdx.x;
    const int grp  = b & 15;              // % NGRP
    const int quad = (b >> 4) & 3;
    const int box  = b >> 6;
    const int qx   = quad & 1;
    const int qy   = quad >> 1;
    const int tid  = threadIdx.x;

    const float* th = theta + box * 6;
    // feature-pixel affine: ix = ax*fx + bxc*fy + cx_, fx,fy in (-1,1)
    const float ax  = th[0] * 64.0f, bxc = th[1] * 64.0f, cx_ = th[2] * 64.0f + 63.5f;
    const float ay  = th[3] * 64.0f, byc = th[4] * 64.0f, cy_ = th[5] * 64.0f + 63.5f;

    // quadrant sample-coordinate bbox (+1 for bilinear upper corner)
    const float fcx = (float)qx - 0.5f;
    const float fcy = (float)qy - 0.5f;
    const float fh  = 31.0f / 64.0f;
    const float cxq = ax * fcx + bxc * fcy + cx_;
    const float cyq = ay * fcx + byc * fcy + cy_;
    const float hxq = (fabsf(ax) + fabsf(bxc)) * fh;
    const float hyq = (fabsf(ay) + fabsf(byc)) * fh;
    const int tx0 = min(max((int)floorf(cxq - hxq), 0), WF - 1);
    const int tx1 = min(max((int)floorf(cxq + hxq) + 1, 0), WF - 1);
    const int ty0 = min(max((int)floorf(cyq - hyq), 0), HF - 1);
    const int ty1 = min(max((int)floorf(cyq + hyq) + 1, 0), HF - 1);
    const int tw  = tx1 - tx0 + 1;
    const int thh = ty1 - ty0 + 1;
    const int twp = tw | 1;               // odd float2-slot row stride
    const int n   = tw * thh;

    // this thread's 4 consecutive-x pixels
    const int r     = tid >> 3;           // 0..31
    const int g     = tid & 7;            // 0..7
    const int y     = (qy << 5) + r;
    const int xbase = (qx << 5) + (g << 2);

    int   pk [4];
    float W00[4], W10[4], W01[4], W11[4];
    {
        float fy = (float)(2 * y + 1) * 0.015625f - 1.0f;
#pragma unroll
        for (int j = 0; j < 4; ++j) {
            int x = xbase + j;
            float fx = (float)(2 * x + 1) * 0.015625f - 1.0f;
            float ix = ax * fx + bxc * fy + cx_;
            float iy = ay * fx + byc * fy + cy_;
            float x0f = floorf(ix), y0f = floorf(iy);
            int x0 = (int)x0f, y0 = (int)y0f;
            float wx1 = ix - x0f, wy1 = iy - y0f;
            float wx0 = 1.0f - wx1, wy0 = 1.0f - wy1;
            bool vx0 = (x0 >= 0) & (x0 < WF);
            bool vx1 = (x0 >= -1) & (x0 < WF - 1);
            bool vy0 = (y0 >= 0) & (y0 < HF);
            bool vy1 = (y0 >= -1) & (y0 < HF - 1);
            W00[j] = (vx0 & vy0) ? wx0 * wy0 : 0.0f;
            W10[j] = (vx1 & vy0) ? wx1 * wy0 : 0.0f;
            W01[j] = (vx0 & vy1) ? wx0 * wy1 : 0.0f;
            W11[j] = (vx1 & vy1) ? wx1 * wy1 : 0.0f;
            int x0c = min(max(x0, 0), WF - 1) - tx0;
            int y0c = min(max(y0, 0), HF - 1) - ty0;
            int x1c = min(max(x0 + 1, 0), WF - 1) - tx0;
            int y1c = min(max(y0 + 1, 0), HF - 1) - ty0;
            int xs = x1c - x0c;           // 0 or 1
            int ys = y1c - y0c;           // 0 or 1
            pk[j] = (y0c * twp + x0c) | (xs << 16) | (ys << 17);
        }
    }

    // tile-loader walking state (no division in the channel loop)
    const int qy0_ = tid / tw;
    const int qx0_ = tid - qy0_ * tw;
    const int kq   = 256 / tw;
    const int rq   = 256 - kq * tw;
    const int lidx0 = qy0_ * twp + qx0_;
    const int gidx0 = (ty0 + qy0_) * WF + tx0 + qx0_;
    const int stepL = kq * twp + rq;
    const int stepG = (kq << 7) + rq;

    const float* fmb = feat + (size_t)(box >> 6) * (size_t)(CCH * HW)
                            + (size_t)(grp * CHG) * HW;
    float* ob = out + (size_t)box * (size_t)(CCH * SSQ)
                    + (size_t)(grp * CHG) * SSQ + y * S + xbase;

    for (int cg = 0; cg < CHG / 2; ++cg) {
        const float* fc = fmb + (size_t)(2 * cg) * HW;
        // ---- stage tile: 2 channels interleaved as float2 ----
        {
            int qx_ = qx0_, lidx = lidx0, gidx = gidx0;
            for (int q = tid; q < n; q += 256) {
                float2 t;
                t.x = fc[gidx];
                t.y = fc[gidx + HW];
                tile[lidx] = t;
                qx_ += rq; lidx += stepL; gidx += stepG;
                if (qx_ >= tw) { qx_ -= tw; lidx += twp - tw; gidx += WF - tw; }
            }
        }
        __syncthreads();
        // ---- sample 4 consecutive px x 2 channels, two float4 stores ----
        float4 v0, v1;
        float* vp0 = &v0.x;
        float* vp1 = &v1.x;
#pragma unroll
        for (int j = 0; j < 4; ++j) {
            int p   = pk[j];
            int a00 = p & 0xFFFF;
            int xs  = (p >> 16) & 1;
            int a01 = a00 + (((p >> 17) & 1) ? twp : 0);
            float2 c00 = tile[a00];
            float2 c10 = tile[a00 + xs];
            float2 c01 = tile[a01];
            float2 c11 = tile[a01 + xs];
            vp0[j] = c00.x * W00[j] + c10.x * W10[j] + c01.x * W01[j] + c11.x * W11[j];
            vp1[j] = c00.y * W00[j] + c10.y * W10[j] + c01.y * W01[j] + c11.y * W11[j];
        }
        float* oc = ob + (size_t)(2 * cg) * SSQ;
        *reinterpret_cast<float4*>(oc)       = v0;
        *reinterpret_cast<float4*>(oc + SSQ) = v1;
        __syncthreads();
    }
}

extern "C" void kernel_launch(void* const* d_in, const int* in_sizes, int n_in,
                              void* d_out, int out_size, void* d_ws, size_t ws_size,
                              hipStream_t stream) {
    const float* feat = (const float*)d_in[0];
    const float* obb  = (const float*)d_in[1];
    float* out = (float*)d_out;
    float* theta_ws = (float*)d_ws;
    float* m_out = out + CROPS_ELEMS;

    prep_kernel<<<1, 128, 0, stream>>>(obb, theta_ws, m_out);
    sample_kernel<<<NBOX * 4 * NGRP, 256, 0, stream>>>(feat, theta_ws, out);
}